// Round 1
// baseline (11007.783 us; speedup 1.0000x reference)
//
#include <hip/hip_runtime.h>
#include <hip/hip_bf16.h>
#include <math.h>

#define DF 128
#define NC 40

__global__ void k_deg_init(float* __restrict__ deg, int N) {
  int i = blockIdx.x * blockDim.x + threadIdx.x;
  if (i < N) deg[i] = 2.0f;  // two self-loops per node (SGC outer + gcn_norm inner)
}

__global__ void k_deg_count(const int* __restrict__ col, float* __restrict__ deg, int E) {
  int e = blockIdx.x * blockDim.x + threadIdx.x;
  if (e < E) unsafeAtomicAdd(&deg[col[e]], 1.0f);
}

__global__ void k_deg_inv(float* __restrict__ deg, int N) {
  int i = blockIdx.x * blockDim.x + threadIdx.x;
  if (i < N) deg[i] = rsqrtf(deg[i]);  // deg >= 2 always, no zero guard needed
}

// y[node] = 2*dinv[node]^2 * x[node]  (both self-loops), 32 threads/node, float4/lane
__global__ void k_hop_init(const float* __restrict__ xin, const float* __restrict__ dinv,
                           float* __restrict__ y, int N) {
  int t = blockIdx.x * blockDim.x + threadIdx.x;
  int node = t >> 5, q = t & 31;
  if (node >= N) return;
  float di = dinv[node];
  float w = 2.0f * di * di;
  float4 v = ((const float4*)(xin + (size_t)node * DF))[q];
  ((float4*)(y + (size_t)node * DF))[q] = make_float4(w*v.x, w*v.y, w*v.z, w*v.w);
}

// per real edge: y[col] += dinv[row]*dinv[col]*x[row], 32 threads/edge, float4/lane
__global__ void k_hop_edges(const int* __restrict__ row, const int* __restrict__ col,
                            const float* __restrict__ dinv, const float* __restrict__ xin,
                            float* __restrict__ y, int E) {
  long long t = (long long)blockIdx.x * blockDim.x + threadIdx.x;
  int e = (int)(t >> 5), q = (int)(t & 31);
  if (e >= E) return;
  int r = row[e], c = col[e];
  float w = dinv[r] * dinv[c];
  float4 v = ((const float4*)(xin + (size_t)r * DF))[q];
  float* yp = y + (size_t)c * DF + q * 4;
  unsafeAtomicAdd(yp + 0, w * v.x);
  unsafeAtomicAdd(yp + 1, w * v.y);
  unsafeAtomicAdd(yp + 2, w * v.z);
  unsafeAtomicAdd(yp + 3, w * v.w);
}

// logits = h @ W^T + b, then log_softmax over 40 classes. One thread per node,
// W (40x128 = 20 KB) staged in LDS; wave-uniform LDS addresses -> broadcast reads.
__global__ __launch_bounds__(128) void k_logits_lsm(
    const float* __restrict__ h, const float* __restrict__ W,
    const float* __restrict__ b, float* __restrict__ out, int N) {
  __shared__ float4 Ws[NC * (DF / 4)];
  __shared__ float bs[NC];
  for (int i = threadIdx.x; i < NC * (DF / 4); i += blockDim.x)
    Ws[i] = ((const float4*)W)[i];
  if (threadIdx.x < NC) bs[threadIdx.x] = b[threadIdx.x];
  __syncthreads();
  int node = blockIdx.x * blockDim.x + threadIdx.x;
  if (node >= N) return;
  float acc[NC];
#pragma unroll
  for (int c = 0; c < NC; ++c) acc[c] = 0.f;
  const float4* xr = (const float4*)(h + (size_t)node * DF);
  for (int d4 = 0; d4 < DF / 4; ++d4) {
    float4 v = xr[d4];
#pragma unroll
    for (int c = 0; c < NC; ++c) {
      float4 wv = Ws[c * (DF / 4) + d4];
      acc[c] += v.x * wv.x + v.y * wv.y + v.z * wv.z + v.w * wv.w;
    }
  }
  float m = -1e30f;
#pragma unroll
  for (int c = 0; c < NC; ++c) { acc[c] += bs[c]; m = fmaxf(m, acc[c]); }
  float s = 0.f;
#pragma unroll
  for (int c = 0; c < NC; ++c) s += expf(acc[c] - m);
  float lse = m + logf(s);
  float* op = out + (size_t)node * NC;
#pragma unroll
  for (int c = 0; c < NC; ++c) op[c] = acc[c] - lse;
}

extern "C" void kernel_launch(void* const* d_in, const int* in_sizes, int n_in,
                              void* d_out, int out_size, void* d_ws, size_t ws_size,
                              hipStream_t stream) {
  const float* x = (const float*)d_in[0];
  const int* ei  = (const int*)d_in[1];   // [2][E] flat: rows then cols
  const float* W = (const float*)d_in[2];
  const float* b = (const float*)d_in[3];
  // d_in[4] is K; reference fixes K=2 — hardcoded below.
  float* out = (float*)d_out;

  const int N = in_sizes[0] / DF;
  const int E = in_sizes[1] / 2;
  const int* row  = ei;
  const int* colv = ei + E;

  // Workspace layout: deg/dinv [N] | buf0 [N*DF] | buf1 [N*DF]  (~103 MB)
  float* deg  = (float*)d_ws;
  float* buf0 = deg + (((size_t)N + 255) & ~(size_t)255);
  float* buf1 = buf0 + (size_t)N * DF;

  const int B = 256;
  k_deg_init<<<(N + B - 1) / B, B, 0, stream>>>(deg, N);
  k_deg_count<<<(E + B - 1) / B, B, 0, stream>>>(colv, deg, E);
  k_deg_inv<<<(N + B - 1) / B, B, 0, stream>>>(deg, N);

  const long long tE = (long long)E * 32;
  const int gE = (int)((tE + B - 1) / B);
  const long long tN = (long long)N * 32;
  const int gN = (int)((tN + B - 1) / B);

  // hop 1: x -> buf0
  k_hop_init <<<gN, B, 0, stream>>>(x, deg, buf0, N);
  k_hop_edges<<<gE, B, 0, stream>>>(row, colv, deg, x, buf0, E);
  // hop 2: buf0 -> buf1
  k_hop_init <<<gN, B, 0, stream>>>(buf0, deg, buf1, N);
  k_hop_edges<<<gE, B, 0, stream>>>(row, colv, deg, buf0, buf1, E);

  k_logits_lsm<<<(N + 127) / 128, 128, 0, stream>>>(buf1, W, b, out, N);
}

// Round 2
// 790.299 us; speedup vs baseline: 13.9286x; 13.9286x over previous
//
#include <hip/hip_runtime.h>
#include <hip/hip_bf16.h>
#include <math.h>

#define DF 128
#define NC 40
#define ST 48          // padded row stride (floats) for 40-dim buffers: 192 B = 3 cache lines
#define SCAN_BLK 256
#define SCAN_ELEMS 1024  // 4 per thread

// ---------- degree ----------
__global__ void k_deg_zero(int* __restrict__ degi, int N) {
  int i = blockIdx.x * blockDim.x + threadIdx.x;
  if (i < N) degi[i] = 0;
}
__global__ void k_deg_count(const int* __restrict__ col, int* __restrict__ degi, int E) {
  int e = blockIdx.x * blockDim.x + threadIdx.x;
  if (e < E) atomicAdd(&degi[col[e]], 1);
}
__global__ void k_dinv(const int* __restrict__ degi, float* __restrict__ dinv, int N) {
  int i = blockIdx.x * blockDim.x + threadIdx.x;
  if (i < N) dinv[i] = rsqrtf((float)degi[i] + 2.0f);  // +2 self-loops
}

// ---------- exclusive scan of degi -> off (3 kernels) ----------
__global__ void k_scan1(const int* __restrict__ degi, int* __restrict__ off,
                        int* __restrict__ blks, int N) {
  __shared__ int s[SCAN_BLK];
  int tid = threadIdx.x;
  int base = blockIdx.x * SCAN_ELEMS + tid * 4;
  int v0 = (base + 0 < N) ? degi[base + 0] : 0;
  int v1 = (base + 1 < N) ? degi[base + 1] : 0;
  int v2 = (base + 2 < N) ? degi[base + 2] : 0;
  int v3 = (base + 3 < N) ? degi[base + 3] : 0;
  int tsum = v0 + v1 + v2 + v3;
  s[tid] = tsum;
  __syncthreads();
  for (int o = 1; o < SCAN_BLK; o <<= 1) {   // Hillis-Steele inclusive
    int t = (tid >= o) ? s[tid - o] : 0;
    __syncthreads();
    s[tid] += t;
    __syncthreads();
  }
  int excl = s[tid] - tsum;
  if (base + 0 < N) off[base + 0] = excl;
  if (base + 1 < N) off[base + 1] = excl + v0;
  if (base + 2 < N) off[base + 2] = excl + v0 + v1;
  if (base + 3 < N) off[base + 3] = excl + v0 + v1 + v2;
  if (tid == SCAN_BLK - 1) blks[blockIdx.x] = s[tid];
}
__global__ void k_scan2(int* __restrict__ blks, int G) {
  if (blockIdx.x == 0 && threadIdx.x == 0) {
    int run = 0;
    for (int i = 0; i < G; ++i) { int t = blks[i]; blks[i] = run; run += t; }
  }
}
__global__ void k_scan3(int* __restrict__ off, int* __restrict__ cur,
                        const int* __restrict__ blks, int N, int E) {
  int i = blockIdx.x * blockDim.x + threadIdx.x;
  if (i < N) {
    int v = off[i] + blks[i >> 10];
    off[i] = v;
    cur[i] = v;
  }
  if (i == 0) off[N] = E;
}

// ---------- CSR scatter: group source indices by destination ----------
__global__ void k_scatter(const int* __restrict__ row, const int* __restrict__ col,
                          int* __restrict__ cur, int* __restrict__ eidx, int E) {
  int e = blockIdx.x * blockDim.x + threadIdx.x;
  if (e < E) {
    int p = atomicAdd(&cur[col[e]], 1);
    eidx[p] = row[e];
  }
}

// ---------- projection first: g0[n] = dinv[n] * (x[n] @ W^T)  [N x 40, stride 48] ----------
__global__ __launch_bounds__(128) void k_xw_scale(
    const float* __restrict__ x, const float* __restrict__ W,
    const float* __restrict__ dinv, float* __restrict__ g0, int N) {
  __shared__ float4 Ws[NC * (DF / 4)];  // 20 KB
  for (int i = threadIdx.x; i < NC * (DF / 4); i += blockDim.x)
    Ws[i] = ((const float4*)W)[i];
  __syncthreads();
  int node = blockIdx.x * blockDim.x + threadIdx.x;
  if (node >= N) return;
  float acc[NC];
#pragma unroll
  for (int c = 0; c < NC; ++c) acc[c] = 0.f;
  const float4* xr = (const float4*)(x + (size_t)node * DF);
  for (int d4 = 0; d4 < DF / 4; ++d4) {
    float4 v = xr[d4];
#pragma unroll
    for (int c = 0; c < NC; ++c) {
      float4 wv = Ws[c * (DF / 4) + d4];
      acc[c] += v.x * wv.x + v.y * wv.y + v.z * wv.z + v.w * wv.w;
    }
  }
  float di = dinv[node];
  float4* gp = (float4*)(g0 + (size_t)node * ST);
#pragma unroll
  for (int c4 = 0; c4 < NC / 4; ++c4)
    gp[c4] = make_float4(di * acc[c4 * 4 + 0], di * acc[c4 * 4 + 1],
                         di * acc[c4 * 4 + 2], di * acc[c4 * 4 + 3]);
}

// ---------- one propagation hop (gather-reduce, no atomics) ----------
// in g-form:  gin[r] = dinv[r]*h[r].  acc = sum_{in-edges} gin[r] + 2*gin[node].
// mode 0 (intermediate hop): out = dinv[node]^2 * acc  (stays in g-form)
// mode 1 (final hop):        out = dinv[node]   * acc  (h-form, ready for bias+lsm)
__global__ __launch_bounds__(256) void k_gather(
    const int* __restrict__ off, const int* __restrict__ eidx,
    const float* __restrict__ dinv, const float* __restrict__ gin,
    float* __restrict__ gout, int N, int mode) {
  int wave = (int)((blockIdx.x * (size_t)blockDim.x + threadIdx.x) >> 6);
  int lane = threadIdx.x & 63;
  if (wave >= N || lane >= NC) return;
  int node = wave;
  int s = off[node], e = off[node + 1];
  float acc = 2.0f * gin[(size_t)node * ST + lane];  // double self-loop term
  int i = s;
  for (; i + 4 <= e; i += 4) {
    int r0 = eidx[i + 0], r1 = eidx[i + 1], r2 = eidx[i + 2], r3 = eidx[i + 3];
    float a0 = gin[(size_t)r0 * ST + lane];
    float a1 = gin[(size_t)r1 * ST + lane];
    float a2 = gin[(size_t)r2 * ST + lane];
    float a3 = gin[(size_t)r3 * ST + lane];
    acc += (a0 + a1) + (a2 + a3);
  }
  for (; i < e; ++i) acc += gin[(size_t)eidx[i] * ST + lane];
  float di = dinv[node];
  float sc = (mode == 0) ? di * di : di;
  gout[(size_t)node * ST + lane] = sc * acc;
}

// ---------- bias + log_softmax ----------
__global__ __launch_bounds__(128) void k_lsm(
    const float* __restrict__ h, const float* __restrict__ b,
    float* __restrict__ out, int N) {
  __shared__ float bs[NC];
  if (threadIdx.x < NC) bs[threadIdx.x] = b[threadIdx.x];
  __syncthreads();
  int node = blockIdx.x * blockDim.x + threadIdx.x;
  if (node >= N) return;
  float v[NC];
  const float4* hp = (const float4*)(h + (size_t)node * ST);
#pragma unroll
  for (int c4 = 0; c4 < NC / 4; ++c4) {
    float4 t = hp[c4];
    v[c4 * 4 + 0] = t.x; v[c4 * 4 + 1] = t.y;
    v[c4 * 4 + 2] = t.z; v[c4 * 4 + 3] = t.w;
  }
  float m = -1e30f;
#pragma unroll
  for (int c = 0; c < NC; ++c) { v[c] += bs[c]; m = fmaxf(m, v[c]); }
  float ssum = 0.f;
#pragma unroll
  for (int c = 0; c < NC; ++c) ssum += expf(v[c] - m);
  float lse = m + logf(ssum);
  float4* op = (float4*)(out + (size_t)node * NC);
#pragma unroll
  for (int c4 = 0; c4 < NC / 4; ++c4)
    op[c4] = make_float4(v[c4 * 4 + 0] - lse, v[c4 * 4 + 1] - lse,
                         v[c4 * 4 + 2] - lse, v[c4 * 4 + 3] - lse);
}

extern "C" void kernel_launch(void* const* d_in, const int* in_sizes, int n_in,
                              void* d_out, int out_size, void* d_ws, size_t ws_size,
                              hipStream_t stream) {
  const float* x = (const float*)d_in[0];
  const int* ei  = (const int*)d_in[1];   // [2][E] flat: rows then cols
  const float* W = (const float*)d_in[2];
  const float* b = (const float*)d_in[3];
  // d_in[4] is K; reference fixes K=2 — hardcoded.
  float* out = (float*)d_out;

  const int N = in_sizes[0] / DF;
  const int E = in_sizes[1] / 2;
  const int* row  = ei;
  const int* colv = ei + E;

  // workspace carve-up (512 B aligned sections)
  char* base = (char*)d_ws;
  auto alloc = [&](size_t bytes) {
    char* p = base;
    base += (bytes + 511) & ~(size_t)511;
    return p;
  };
  float* dinv = (float*)alloc((size_t)N * 4);
  int*   degi = (int*)  alloc((size_t)N * 4);
  int*   off  = (int*)  alloc(((size_t)N + 1) * 4);
  int*   cur  = (int*)  alloc((size_t)N * 4);
  int*   blks = (int*)  alloc(1024 * 4);
  int*   eidx = (int*)  alloc((size_t)E * 4);
  float* g0   = (float*)alloc((size_t)N * ST * 4);
  float* g1   = (float*)alloc((size_t)N * ST * 4);
  float* h2   = (float*)alloc((size_t)N * ST * 4);

  const int B = 256;
  const int gN = (N + B - 1) / B;
  const int gE = (E + B - 1) / B;
  const int G  = (N + SCAN_ELEMS - 1) / SCAN_ELEMS;

  // degree + normalization
  k_deg_zero <<<gN, B, 0, stream>>>(degi, N);
  k_deg_count<<<gE, B, 0, stream>>>(colv, degi, E);
  k_dinv     <<<gN, B, 0, stream>>>(degi, dinv, N);

  // CSR by destination
  k_scan1<<<G, SCAN_BLK, 0, stream>>>(degi, off, blks, N);
  k_scan2<<<1, 64, 0, stream>>>(blks, G);
  k_scan3<<<gN, B, 0, stream>>>(off, cur, blks, N, E);
  k_scatter<<<gE, B, 0, stream>>>(row, colv, cur, eidx, E);

  // project 128 -> 40 first (propagation commutes with the linear layer)
  k_xw_scale<<<(N + 127) / 128, 128, 0, stream>>>(x, W, dinv, g0, N);

  // two hops, gather-reduce
  const int gWave = (int)(((size_t)N * 64 + B - 1) / B);
  k_gather<<<gWave, B, 0, stream>>>(off, eidx, dinv, g0, g1, N, 0);
  k_gather<<<gWave, B, 0, stream>>>(off, eidx, dinv, g1, h2, N, 1);

  // bias + log_softmax
  k_lsm<<<(N + 127) / 128, 128, 0, stream>>>(h2, b, out, N);
}